// Round 7
// baseline (154.477 us; speedup 1.0000x reference)
//
#include <hip/hip_runtime.h>
#include <hip/hip_cooperative_groups.h>

namespace cg = cooperative_groups;

// Problem: N=4096 rows, D=64 feats, 10 classes.
// sym KL: sym_ij = 0.25*(H_i . Hp_j + s_i + s_j + det_ij + det_ji - 128)
// per-feature packed K layout (K=256):
//   H[r][4d+{0,1,2,3}] = { var+mu^2, -2mu, 1/var, mu/var }   (F0,F1,G0,G1)
// Hp is NOT stored: Hp[e] = H[pi(e)], pi swaps c<->c+2 per 4-group; pi is an
// involution, so H_i . Hp_j = sum_e H_i[e]*H_j[pi(e)], and pi on a lane's
// 8-elem fragment is the 32-bit register permutation [v1,v0,v3,v2].
//
// Storage is MFMA-FRAGMENT-MAJOR: Hf[tile=r>>5][k=e>>4][(r&31)*16 + (e&15)]
// so each k-step fragment load is 64 lanes x 16 B = 1 KB contiguous.
//
// R7 vs R6: R6's per-block threadfence + hot-address ACQ_REL counter cost
// +13us (cross-XCD L2 writeback per block + cacheline ping-pong). Reverted
// to R5 math/structure, but fused all three kernels into ONE cooperative
// launch: precompute -> grid.sync -> 528 pair tiles striped over 256 blocks
// -> grid.sync -> block-0 final reduce. Grid syncs are collective (amortized
// release/acquire), replacing 2 launch boundaries + the 1-block tail kernel.

#define N 4096
#define D 64
#define KH 256
#define MT 128             // pair block tile side
#define TILES2 32          // 4096/128
#define NBLK2 528          // TILES2*(TILES2+1)/2 upper-tri blocks
#define GRID 256           // cooperative grid size (<= co-residency bound)
#define DET_EPS 1e-8f

typedef short bf16x8 __attribute__((ext_vector_type(8)));
typedef float f32x16 __attribute__((ext_vector_type(16)));

// ws byte layout
#define WS_H    0                       // ushort[N/32][16][512] = 2 MB (frag-major)
#define WS_PSL  (N * KH * 2)            // float4[N] = 64 KB
#define WS_PART (WS_PSL + N * 16)       // float[2*NBLK2]

static __device__ __forceinline__ unsigned short f2bf(float x) {
  // round-to-nearest-even bf16
  unsigned int u = __float_as_uint(x);
  unsigned int r = (u + 0x7FFFu + ((u >> 16) & 1u)) >> 16;
  return (unsigned short)r;
}

static __device__ __forceinline__ f32x16 mfma_bf16(bf16x8 a, bf16x8 b, f32x16 c) {
  return __builtin_amdgcn_mfma_f32_32x32x16_bf16(a, b, c, 0, 0, 0);
}

// ---------------------------------------------------------------------------
// One cooperative kernel, three phases.
__global__ __launch_bounds__(256, 2) void fused_kernel(
    const float* __restrict__ mu, const float* __restrict__ var,
    const int* __restrict__ labels,
    unsigned short* __restrict__ Hf, float4* __restrict__ PSL,
    float* __restrict__ partial, float* __restrict__ out) {
  cg::grid_group grid = cg::this_grid();

  __shared__ float4 sPi[128];
  __shared__ float4 sPj[128];
  __shared__ float red[8];
  __shared__ float redp[4], redn[4];

  const int t = threadIdx.x;
  const int lane = t & 63;
  const int w = t >> 6;               // 0..3

  // ----- Phase 1: per-row precompute; 256 blocks x 16 rows each. -----
  {
    #pragma unroll
    for (int rep = 0; rep < 4; ++rep) {
      const int r = (int)blockIdx.x * 16 + rep * 4 + w;
      const float m = mu[r * D + lane];
      const float v = var[r * D + lane];
      const float g0 = 1.0f / v;
      const float f0 = v + m * m;
      const float f1 = -2.0f * m;
      const float g1 = m * g0;

      // element e = 4*d + c; frag-major idx:
      //   (r>>5)*8192 + (e>>4)*512 + (r&31)*16 + (e&15)
      const size_t base = (size_t)(r >> 5) * 8192 + (size_t)(lane >> 2) * 512
                          + (size_t)(r & 31) * 16 + (size_t)(lane & 3) * 4;
      *(ushort4*)&Hf[base] = make_ushort4(f2bf(f0), f2bf(f1), f2bf(g0), f2bf(g1));

      float p = v;
      float s = m * m * g0;
      #pragma unroll
      for (int off = 1; off < 64; off <<= 1) {
        p *= __shfl_xor(p, off);
        s += __shfl_xor(s, off);
      }
      if (lane == 0) {
        PSL[r] = make_float4(p, 1.0f / (p + DET_EPS), 0.25f * s - 16.0f,
                             (float)labels[r]);
      }
    }
  }

  grid.sync();

  // ----- Phase 2: upper-tri 128x128 pair tiles, striped over the grid. -----
  const int sr = w >> 1, sc = w & 1;  // 64x64 quadrant of the 128x128 block
  const int l31 = lane & 31;
  const int slot = l31 * 16 + (lane >> 5) * 8;  // frag-major lane slot

  for (int L = (int)blockIdx.x; L < NBLK2; L += GRID) {
    // triangular decode: L -> (it, jt), it <= jt  (32x32 tile grid)
    int it = (int)(32.5f - sqrtf(32.5f * 32.5f - 2.0f * (float)L));
    while (it > 0 && L < it * TILES2 - it * (it - 1) / 2) --it;
    while (L >= (it + 1) * TILES2 - (it + 1) * it / 2) ++it;
    const int jt = it + (L - (it * TILES2 - it * (it - 1) / 2));
    const int i0 = it * MT, j0 = jt * MT;

    __syncthreads();   // protect sPi/sPj from previous iteration's readers
    if (t < 128) sPi[t] = PSL[i0 + t];
    else sPj[t - 128] = PSL[j0 + t - 128];
    __syncthreads();

    const unsigned short* pa = Hf + (size_t)(i0 / 32 + sr * 2) * 8192 + slot;
    const unsigned short* pb = Hf + (size_t)(j0 / 32 + sc * 2) * 8192 + slot;

    // diagonal big-tile: quadrant (1,0) is entirely below the diagonal
    const bool active = !(it == jt && w == 2);

    f32x16 C00 = {}, C01 = {}, C10 = {}, C11 = {};
    float pos = 0.0f, neg = 0.0f;

    if (active) {
      #pragma unroll 4
      for (int k = 0; k < 16; ++k) {
        const bf16x8 a0 = *(const bf16x8*)(pa + k * 512);
        const bf16x8 a1 = *(const bf16x8*)(pa + 8192 + k * 512);
        const bf16x8 c0 = *(const bf16x8*)(pb + k * 512);
        const bf16x8 c1 = *(const bf16x8*)(pb + 8192 + k * 512);
        // pi(e): swap component pairs -> 32-bit reg perm [v1,v0,v3,v2]
        const bf16x8 b0 = __builtin_shufflevector(c0, c0, 2, 3, 0, 1, 6, 7, 4, 5);
        const bf16x8 b1 = __builtin_shufflevector(c1, c1, 2, 3, 0, 1, 6, 7, 4, 5);
        C00 = mfma_bf16(a0, b0, C00);
        C01 = mfma_bf16(a0, b1, C01);
        C10 = mfma_bf16(a1, b0, C10);
        C11 = mfma_bf16(a1, b1, C11);
      }

      // epilogue: C/D layout col=lane&31, row=(r&3)+8*(r>>2)+4*(lane>>5)
      const int rbase = 4 * (lane >> 5);
      #pragma unroll
      for (int mn = 0; mn < 4; ++mn) {
        const int m = mn >> 1, n = mn & 1;
        const f32x16 C = (mn == 0) ? C00 : (mn == 1) ? C01 : (mn == 2) ? C10 : C11;
        const int jloc = (sc * 2 + n) * 32 + l31;
        const int j = j0 + jloc;
        const float4 pj = sPj[jloc];
        #pragma unroll
        for (int r = 0; r < 16; ++r) {
          const int row = (r & 3) + 8 * (r >> 2) + rbase;
          const int iloc = (sr * 2 + m) * 32 + row;
          const int i = i0 + iloc;
          if (i < j) {                 // strict upper triangle only
            const float4 pi = sPi[iloc];
            const float det = pj.x * pi.y + pi.x * pj.y;
            const float sym = 0.25f * (C[r] + det) + pi.z + pj.z;
            const float sig = __builtin_amdgcn_rcpf(1.0f + __expf(-sym));
            if (pi.w == pj.w) pos += sig; else neg += sig;
          }
        }
      }
    }

    // wave reduce -> LDS -> per-tile private slot store (no contended atomics)
    #pragma unroll
    for (int off = 32; off > 0; off >>= 1) {
      pos += __shfl_down(pos, off);
      neg += __shfl_down(neg, off);
    }
    if (lane == 0) { red[w] = pos; red[4 + w] = neg; }
    __syncthreads();
    if (t == 0) {
      partial[L]         = red[0] + red[1] + red[2] + red[3];
      partial[NBLK2 + L] = red[4] + red[5] + red[6] + red[7];
    }
  }

  grid.sync();

  // ----- Phase 3: block 0 reduces all partials, writes the 4 outputs. -----
  if (blockIdx.x == 0) {
    float p = 0.0f, n = 0.0f;
    for (int i = t; i < NBLK2; i += 256) {
      p += __hip_atomic_load(&partial[i], __ATOMIC_RELAXED,
                             __HIP_MEMORY_SCOPE_AGENT);
      n += __hip_atomic_load(&partial[NBLK2 + i], __ATOMIC_RELAXED,
                             __HIP_MEMORY_SCOPE_AGENT);
    }
    #pragma unroll
    for (int off = 32; off > 0; off >>= 1) {
      p += __shfl_down(p, off);
      n += __shfl_down(n, off);
    }
    if (lane == 0) { redp[w] = p; redn[w] = n; }
    __syncthreads();
    if (t == 0) {
      const float posS = 2.0f * (redp[0] + redp[1] + redp[2] + redp[3]);
      const float negS = 2.0f * (redn[0] + redn[1] + redn[2] + redn[3]);
      out[0] = posS * (1.0f / 16777216.0f);  // mean over N*N = 2^24
      out[1] = negS * (1.0f / 16777216.0f);
      out[2] = posS;
      out[3] = negS;
    }
  }
}

extern "C" void kernel_launch(void* const* d_in, const int* in_sizes, int n_in,
                              void* d_out, int out_size, void* d_ws, size_t ws_size,
                              hipStream_t stream) {
  const float* mu = (const float*)d_in[0];
  const float* var = (const float*)d_in[1];
  const int* labels = (const int*)d_in[2];
  float* out = (float*)d_out;
  char* ws = (char*)d_ws;

  unsigned short* Hf = (unsigned short*)(ws + WS_H);
  float4* PSL = (float4*)(ws + WS_PSL);
  float* partial = (float*)(ws + WS_PART);

  void* args[] = {(void*)&mu, (void*)&var, (void*)&labels,
                  (void*)&Hf, (void*)&PSL, (void*)&partial, (void*)&out};
  hipLaunchCooperativeKernel((const void*)fused_kernel, dim3(GRID), dim3(256),
                             args, 0, stream);
}

// Round 8
// 78.846 us; speedup vs baseline: 1.9592x; 1.9592x over previous
//
#include <hip/hip_runtime.h>

// Problem: N=4096 rows, D=64 feats, 10 classes.
// sym KL: sym_ij = 0.25*(H_i . Hp_j + s_i + s_j + det_ij + det_ji - 128)
// per-feature packed K layout (K=256):
//   H[r][4d+{0,1,2,3}] = { var+mu^2, -2mu, 1/var, mu/var }   (F0,F1,G0,G1)
// Hp is NOT stored: Hp[e] = H[pi(e)], pi swaps c<->c+2 per 4-group; pi is an
// involution, so H_i . Hp_j = sum_e H_i[e]*H_j[pi(e)], and pi on a lane's
// 8-elem fragment is the 32-bit register permutation [v1,v0,v3,v2].
//
// Storage is MFMA-FRAGMENT-MAJOR: Hf[tile=r>>5][k=e>>4][(r&31)*16 + (e&15)]
// so each k-step fragment load is 64 lanes x 16 B = 1 KB contiguous.
//
// R8: exact revert to R5 (78.8 us, best verified). R6 (last-block-done:
// per-block threadfence + hot ACQ_REL counter, +13us) and R7 (cooperative
// grid.sync, +76us: two grid syncs alone cost ~70us on 8-XCD gfx950) both
// proved cross-XCD sync primitives are tens-of-us; stream-ordered kernel
// boundaries are the cheapest global barrier. Kernel-side time is ~10us over
// a ~69us harness-fixed floor (256MiB ws poison fill + restores).

#define N 4096
#define D 64
#define KH 256
#define MT 128             // pair block tile side
#define TILES2 32          // 4096/128
#define NBLK2 528          // TILES2*(TILES2+1)/2 upper-tri blocks
#define DET_EPS 1e-8f

typedef short bf16x8 __attribute__((ext_vector_type(8)));
typedef float f32x16 __attribute__((ext_vector_type(16)));

// ws byte layout
#define WS_H    0                       // ushort[N/32][16][512] = 2 MB (frag-major)
#define WS_PSL  (N * KH * 2)            // float4[N] = 64 KB
#define WS_PART (WS_PSL + N * 16)       // float[2*NBLK2]

static __device__ __forceinline__ unsigned short f2bf(float x) {
  // round-to-nearest-even bf16
  unsigned int u = __float_as_uint(x);
  unsigned int r = (u + 0x7FFFu + ((u >> 16) & 1u)) >> 16;
  return (unsigned short)r;
}

static __device__ __forceinline__ f32x16 mfma_bf16(bf16x8 a, bf16x8 b, f32x16 c) {
  return __builtin_amdgcn_mfma_f32_32x32x16_bf16(a, b, c, 0, 0, 0);
}

// ---------------------------------------------------------------------------
// Kernel 1: per-row precompute. 1024 blocks x 256 thr; one wave per row.
// Stores Hf (frag-major) and PSL = {p, 1/(p+eps), 0.25*s-16, label}.
__global__ __launch_bounds__(256) void precompute_kernel(
    const float* __restrict__ mu, const float* __restrict__ var,
    const int* __restrict__ labels,
    unsigned short* __restrict__ Hf, float4* __restrict__ PSL) {
  const int t = threadIdx.x;
  const int lane = t & 63;   // feature d
  const int w = t >> 6;
  const int r = blockIdx.x * 4 + w;

  const float m = mu[r * D + lane];
  const float v = var[r * D + lane];
  const float g0 = 1.0f / v;
  const float f0 = v + m * m;
  const float f1 = -2.0f * m;
  const float g1 = m * g0;

  // element e = 4*d + c; frag-major idx:
  //   (r>>5)*8192 + (e>>4)*512 + (r&31)*16 + (e&15)
  // lane d writes e = 4d..4d+3 -> 4 contiguous ushorts.
  const size_t base = (size_t)(r >> 5) * 8192 + (size_t)(lane >> 2) * 512
                      + (size_t)(r & 31) * 16 + (size_t)(lane & 3) * 4;
  *(ushort4*)&Hf[base] = make_ushort4(f2bf(f0), f2bf(f1), f2bf(g0), f2bf(g1));

  // wave reductions: p = prod var, s = sum mu^2/var
  float p = v;
  float s = m * m * g0;
  #pragma unroll
  for (int off = 1; off < 64; off <<= 1) {
    p *= __shfl_xor(p, off);
    s += __shfl_xor(s, off);
  }
  if (lane == 0) {
    PSL[r] = make_float4(p, 1.0f / (p + DET_EPS), 0.25f * s - 16.0f,
                         (float)labels[r]);
  }
}

// ---------------------------------------------------------------------------
// Kernel 2: upper-tri 128x128 pair tiles. 4 waves; wave w = quadrant
// (sr=w>>1, sc=w&1), each wave computes a 2x2 grid of 32x32 MFMA subtiles.
// B fragments derived from H via in-register component swap (see header).
__global__ __launch_bounds__(256, 2) void pair_kernel(
    const unsigned short* __restrict__ Hf,
    const float4* __restrict__ PSL, float* __restrict__ partial) {
  __shared__ float4 sPi[128];
  __shared__ float4 sPj[128];
  __shared__ float red[8];

  // triangular decode: block L -> (it, jt), it <= jt  (32x32 tile grid)
  int L = (int)blockIdx.x;
  int it = (int)(32.5f - sqrtf(32.5f * 32.5f - 2.0f * (float)L));
  while (it > 0 && L < it * TILES2 - it * (it - 1) / 2) --it;
  while (L >= (it + 1) * TILES2 - (it + 1) * it / 2) ++it;
  const int jt = it + (L - (it * TILES2 - it * (it - 1) / 2));
  const int i0 = it * MT, j0 = jt * MT;

  const int t = threadIdx.x;
  const int lane = t & 63;
  const int w = t >> 6;               // 0..3
  const int sr = w >> 1, sc = w & 1;  // 64x64 quadrant of the 128x128 block

  // stage per-row stats {p, 1/(p+eps), 0.25*s-16, label}
  if (t < 128) sPi[t] = PSL[i0 + t];
  else sPj[t - 128] = PSL[j0 + t - 128];
  __syncthreads();

  const int l31 = lane & 31;
  const int slot = l31 * 16 + (lane >> 5) * 8;  // frag-major lane slot
  const unsigned short* pa = Hf + (size_t)(i0 / 32 + sr * 2) * 8192 + slot;
  const unsigned short* pb = Hf + (size_t)(j0 / 32 + sc * 2) * 8192 + slot;

  // diagonal big-tile: quadrant (1,0) is entirely below the diagonal
  const bool active = !(it == jt && w == 2);

  f32x16 C00 = {}, C01 = {}, C10 = {}, C11 = {};
  float pos = 0.0f, neg = 0.0f;

  if (active) {
    #pragma unroll 4
    for (int k = 0; k < 16; ++k) {
      const bf16x8 a0 = *(const bf16x8*)(pa + k * 512);
      const bf16x8 a1 = *(const bf16x8*)(pa + 8192 + k * 512);
      const bf16x8 c0 = *(const bf16x8*)(pb + k * 512);
      const bf16x8 c1 = *(const bf16x8*)(pb + 8192 + k * 512);
      // pi(e): swap component pairs -> 32-bit reg perm [v1,v0,v3,v2]
      const bf16x8 b0 = __builtin_shufflevector(c0, c0, 2, 3, 0, 1, 6, 7, 4, 5);
      const bf16x8 b1 = __builtin_shufflevector(c1, c1, 2, 3, 0, 1, 6, 7, 4, 5);
      C00 = mfma_bf16(a0, b0, C00);
      C01 = mfma_bf16(a0, b1, C01);
      C10 = mfma_bf16(a1, b0, C10);
      C11 = mfma_bf16(a1, b1, C11);
    }

    // epilogue: C/D layout col=lane&31, row=(r&3)+8*(r>>2)+4*(lane>>5)
    const int rbase = 4 * (lane >> 5);
    #pragma unroll
    for (int mn = 0; mn < 4; ++mn) {
      const int m = mn >> 1, n = mn & 1;
      const f32x16 C = (mn == 0) ? C00 : (mn == 1) ? C01 : (mn == 2) ? C10 : C11;
      const int jloc = (sc * 2 + n) * 32 + l31;
      const int j = j0 + jloc;
      const float4 pj = sPj[jloc];
      #pragma unroll
      for (int r = 0; r < 16; ++r) {
        const int row = (r & 3) + 8 * (r >> 2) + rbase;
        const int iloc = (sr * 2 + m) * 32 + row;
        const int i = i0 + iloc;
        if (i < j) {                   // strict upper triangle only
          const float4 pi = sPi[iloc];
          const float det = pj.x * pi.y + pi.x * pj.y;
          const float sym = 0.25f * (C[r] + det) + pi.z + pj.z;
          const float sig = __builtin_amdgcn_rcpf(1.0f + __expf(-sym));
          if (pi.w == pj.w) pos += sig; else neg += sig;
        }
      }
    }
  }

  // wave reduce -> LDS -> per-block private slot store (no contended atomics)
  #pragma unroll
  for (int off = 32; off > 0; off >>= 1) {
    pos += __shfl_down(pos, off);
    neg += __shfl_down(neg, off);
  }
  if (lane == 0) { red[w] = pos; red[4 + w] = neg; }
  __syncthreads();
  if (t == 0) {
    partial[L]         = red[0] + red[1] + red[2] + red[3];
    partial[NBLK2 + L] = red[4] + red[5] + red[6] + red[7];
  }
}

// ---------------------------------------------------------------------------
// Kernel 3: reduce per-block slots, finalize 4 outputs.
// Full-grid sums = 2 * triangle sums (sym matrix, diag excluded).
__global__ __launch_bounds__(256) void finalize_kernel(
    const float* __restrict__ partial, float* __restrict__ out) {
  __shared__ float redp[4], redn[4];
  const int t = threadIdx.x;
  const int lane = t & 63, w = t >> 6;
  float p = 0.0f, n = 0.0f;
  for (int i = t; i < NBLK2; i += 256) {
    p += partial[i];
    n += partial[NBLK2 + i];
  }
  #pragma unroll
  for (int off = 32; off > 0; off >>= 1) {
    p += __shfl_down(p, off);
    n += __shfl_down(n, off);
  }
  if (lane == 0) { redp[w] = p; redn[w] = n; }
  __syncthreads();
  if (t == 0) {
    const float pos = 2.0f * (redp[0] + redp[1] + redp[2] + redp[3]);
    const float neg = 2.0f * (redn[0] + redn[1] + redn[2] + redn[3]);
    out[0] = pos * (1.0f / 16777216.0f);  // mean over N*N = 2^24
    out[1] = neg * (1.0f / 16777216.0f);
    out[2] = pos;
    out[3] = neg;
  }
}

extern "C" void kernel_launch(void* const* d_in, const int* in_sizes, int n_in,
                              void* d_out, int out_size, void* d_ws, size_t ws_size,
                              hipStream_t stream) {
  const float* mu = (const float*)d_in[0];
  const float* var = (const float*)d_in[1];
  const int* labels = (const int*)d_in[2];
  float* out = (float*)d_out;
  char* ws = (char*)d_ws;

  unsigned short* Hf = (unsigned short*)(ws + WS_H);
  float4* PSL = (float4*)(ws + WS_PSL);
  float* partial = (float*)(ws + WS_PART);

  precompute_kernel<<<dim3(N / 4), dim3(256), 0, stream>>>(mu, var, labels, Hf, PSL);
  pair_kernel<<<dim3(NBLK2), dim3(256), 0, stream>>>(Hf, PSL, partial);
  finalize_kernel<<<dim3(1), dim3(256), 0, stream>>>(partial, out);
}